// Round 9
// baseline (135.121 us; speedup 1.0000x reference)
//
#include <hip/hip_runtime.h>

#define BATCH 16
#define NN    256
#define E     128
#define NR    (BATCH*NN)
#define ZCAP  8

typedef float f4 __attribute__((ext_vector_type(4)));

// =====================================================================
// THREE kernels (r8 structure). Round-9 theme: halve LDS broadcast ops.
//  k_p1: s3 via wave-uniform f4 loads from Ws (no LDS staging);
//        s13 matvec col-blocked: 8 waves x 2 rows, each lane computes
//        cols l and l+64 -> each (row,k) LDS fragment read ONCE (1024
//        b128 = byte floor, was 2048).
//  k_p2: unchanged (proven recurrence body).
//  k_p3: theta7 matvec col-blocked the same way (512 b128, was 1024).
// VGPR must stay <=64 (1024-thr block); watch WRITE_SIZE for spills.
// Bench metric = kernel sum + ~82us fixed harness workspace-fill.
// =====================================================================

__global__ __launch_bounds__(1024) void k_p1(
    const float* __restrict__ xv,  const float* __restrict__ Ws,
    const float* __restrict__ t1w, const float* __restrict__ t1b,
    const float* __restrict__ t3w, const float* __restrict__ t3b,
    const float* __restrict__ t4w, const float* __restrict__ t4b,
    const float* __restrict__ lw,  const float* __restrict__ lb,
    float* __restrict__ s13g, int* __restrict__ zcnt)
{
    const int blk = blockIdx.x;
    const int b   = blk >> 4;
    const int bt  = blk & 15;
    const int j0  = bt * 16;
    const int r0  = b*NN + j0;
    const int t   = threadIdx.x;
    const int e   = t & 127;
    const int q   = t >> 7;                // 0..7
    const int w   = t >> 6;                // wave 0..15
    const int l   = t & 63;

    __shared__ __align__(16) float s3p[2][16][E]; // s3 i-half partials
    __shared__ __align__(16) float s3l[16][E];    // s3 [col][k]
    __shared__ __align__(16) float hsl[16][E];    // hs [row][k]
    __shared__ int lcnt[16];

    const float* wb = Ws + (size_t)b*NN*NN;

    {   // hs: thread (e,q) -> rows 2q, 2q+1
        float b1 = t1b[e];
        float w0=t1w[e],w1=t1w[E+e],w2=t1w[2*E+e],w3=t1w[3*E+e],w4=t1w[4*E+e];
        #pragma unroll
        for (int rr = 0; rr < 2; ++rr) {
            const float* x = xv + (size_t)(r0 + q*2 + rr)*5;
            hsl[q*2+rr][e] =
                fmaxf(b1 + x[0]*w0+x[1]*w1+x[2]*w2+x[3]*w3+x[4]*w4, 0.f);
        }
    }
    {   // conn-zero scan: wave w -> row j0+w; register shuffle-reduce
        f4 v = *(const f4*)(wb + (size_t)(j0 + w)*NN + l*4);
        int c = (v.x<=0.f) + (v.y<=0.f) + (v.z<=0.f) + (v.w<=0.f);
        #pragma unroll
        for (int off = 32; off; off >>= 1) c += __shfl_down(c, off, 64);
        if (l == 0) lcnt[w] = c;
    }
    {   // s3 partials, direct from Ws: q-group (cq=q&3 -> cols cq*4..+4,
        // ih=q>>2 -> i-half); per-lane (a,c) = t4 at e. Wave-uniform f4
        // loads (L1-cached, off the LDS pipe).
        const int cq = q & 3, ih = q >> 2;
        const float a = t4w[e], c = t4b[e];
        const float* wcol = wb + (size_t)(ih*128)*NN + j0 + cq*4;
        float x0=0.f, x1=0.f, x2=0.f, x3=0.f;
        #pragma unroll 8
        for (int i = 0; i < 128; ++i) {
            f4 wv = *(const f4*)(wcol + (size_t)i*NN);
            x0 += fmaxf(wv.x*a + c, 0.f);
            x1 += fmaxf(wv.y*a + c, 0.f);
            x2 += fmaxf(wv.z*a + c, 0.f);
            x3 += fmaxf(wv.w*a + c, 0.f);
        }
        s3p[ih][cq*4+0][e] = x0;
        s3p[ih][cq*4+1][e] = x1;
        s3p[ih][cq*4+2][e] = x2;
        s3p[ih][cq*4+3][e] = x3;
    }
    __syncthreads();
    {   // combine i-halves: thread (e,q) -> cols 2q, 2q+1
        s3l[2*q][e]   = s3p[0][2*q][e]   + s3p[1][2*q][e];
        s3l[2*q+1][e] = s3p[0][2*q+1][e] + s3p[1][2*q+1][e];
    }
    __syncthreads();
    if (w < 8) {
        // s13 matvec, col-blocked: wave w -> rows 2w, 2w+1;
        // lane l -> output cols l and l+64. Each (row,k0) b128 read once.
        const int ra = 2*w, rb = 2*w + 1;
        float a00=0.f, a01=0.f, a10=0.f, a11=0.f;   // [row][colhalf]
        #pragma unroll 2
        for (int k0 = 0; k0 < E; k0 += 4) {
            f4 h0 = *(const f4*)&hsl[ra][k0];
            f4 h1 = *(const f4*)&hsl[rb][k0];
            f4 s0 = *(const f4*)&s3l[ra][k0];
            f4 s1 = *(const f4*)&s3l[rb][k0];
            #pragma unroll
            for (int m = 0; m < 4; ++m) {
                float wlA = lw[(k0+m)*E + l],      w3A = t3w[(k0+m)*E + l];
                float wlB = lw[(k0+m)*E + l + 64], w3B = t3w[(k0+m)*E + l + 64];
                a00 += h0[m]*wlA + s0[m]*w3A;
                a01 += h0[m]*wlB + s0[m]*w3B;
                a10 += h1[m]*wlA + s1[m]*w3A;
                a11 += h1[m]*wlB + s1[m]*w3B;
            }
        }
        float bA = lb[l] + t3b[l], bB = lb[l+64] + t3b[l+64];
        s13g[(size_t)(r0+ra)*E + l]      = a00 + bA;
        s13g[(size_t)(r0+ra)*E + l + 64] = a01 + bB;
        s13g[(size_t)(r0+rb)*E + l]      = a10 + bA;
        s13g[(size_t)(r0+rb)*E + l + 64] = a11 + bB;
    }
    if (t < 16) zcnt[r0 + t] = lcnt[t];
}

__global__ __launch_bounds__(1024) void k_p2(
    const float* __restrict__ Ws,
    const float* __restrict__ t2w, const float* __restrict__ t2b,
    const float* __restrict__ t5w,
    const float* __restrict__ t6w, const float* __restrict__ t6b,
    const float* __restrict__ s13g, const int* __restrict__ zcnt,
    float* __restrict__ s2b3g, float* __restrict__ gsumG,
    float* __restrict__ zmu4g)
{
    const int b = blockIdx.x;
    const int t = threadIdx.x;
    const int e = t & 127;
    const int q = t >> 7;                  // 0..7
    const size_t bb = (size_t)b*NN*E;

    __shared__ __align__(16) float sQA[8][E];     // colsum partials
    __shared__ __align__(16) float sQB[8][E];     // matvec partials
    __shared__ __align__(16) float dbuf[E], s2bL[E];
    __shared__ float zmuP[ZCAP][E], zmuN[ZCAP][E];
    __shared__ int   zmap[NN];
    __shared__ int   zlist[ZCAP];
    __shared__ int   nzs;
    __shared__ float sg2[2];

    const float* wb = Ws + (size_t)b*NN*NN;

    if (t == 0) nzs = 0;
    if (t < NN) zmap[t] = -1;
    __syncthreads();
    if (t < NN) {
        if (zcnt[b*NN + t] > 0) {
            int s = atomicAdd(&nzs, 1);
            if (s < ZCAP) { zlist[s] = t; zmap[t] = s; }
        }
    }
    __syncthreads();
    const int nz = nzs < ZCAP ? nzs : ZCAP;

    // whole-batch s13 in registers: thread (e,q) -> rows q*32..+32
    float reg[32];
    #pragma unroll
    for (int j = 0; j < 32; ++j)
        reg[j] = s13g[bb + (size_t)(q*32+j)*E + e];

    float s2b_r  = t2b[e];       // s2(it+1) for current it, in registers
    float s2bP_r = s2b_r;

    for (int it = 0; it < 4; ++it) {
        // -------- zero-row machinery (nz==0 on this dataset) --------
        if (nz > 0) {
            if (q == 0) s2bL[e] = s2b_r;
            __syncthreads();
            for (int z = 0; z < nz; ++z) {
                int j = zlist[z];
                float cp = 0.f;
                const float* wr = wb + (size_t)j*NN;
                if (it > 0) {
                    #pragma unroll
                    for (int u = 0; u < 32; ++u) {
                        int i = q*32 + u;
                        if (wr[i] <= 0.f) {
                            int zi = zmap[i];
                            cp += (zi >= 0) ? zmuP[zi][e]
                                            : fmaxf(reg[u] + s2bP_r, 0.f);
                        }
                    }
                }
                sQA[q][e] = cp;
                __syncthreads();
                if (q == 0) {
                    float s = 0.f;
                    #pragma unroll
                    for (int qq = 0; qq < 8; ++qq) s += sQA[qq][e];
                    dbuf[e] = s;
                }
                __syncthreads();
                float cb = 0.f;
                #pragma unroll 2
                for (int k = 0; k < E; k += 4) {
                    f4 d = *(const f4*)&dbuf[k];
                    cb += d.x*t2w[(k+0)*E+e] + d.y*t2w[(k+1)*E+e]
                        + d.z*t2w[(k+2)*E+e] + d.w*t2w[(k+3)*E+e];
                }
                if (q == 0) {
                    float sj = s13g[bb+(size_t)j*E+e];
                    zmuN[z][e] = fmaxf(sj + s2b_r - cb, 0.f);
                }
                __syncthreads();
            }
        }

        // -------- colsum partial over my 32 rows --------
        float csp = 0.f;
        #pragma unroll
        for (int u = 0; u < 32; ++u) csp += fmaxf(reg[u] + s2b_r, 0.f);
        sQA[q][e] = csp;
        __syncthreads();                                   // B1

        // -------- consumer-redundant cs reduce + matvec partial --------
        // it<3: W=t2w (next s2b);  it==3: W=t6w (gsum)
        const float* W = (it < 3) ? t2w : t6w;
        float pa = 0.f;
        #pragma unroll
        for (int g4 = 0; g4 < 4; ++g4) {
            const int k0 = q*16 + g4*4;
            f4 c = *(const f4*)&sQA[0][k0];
            #pragma unroll
            for (int qq = 1; qq < 8; ++qq) {
                f4 d = *(const f4*)&sQA[qq][k0];
                c.x += d.x; c.y += d.y; c.z += d.z; c.w += d.w;
            }
            if (nz > 0) {
                for (int z = 0; z < nz; ++z) {
                    int j = zlist[z];
                    #pragma unroll
                    for (int m = 0; m < 4; ++m) {
                        float sj = s13g[bb+(size_t)j*E + k0 + m];
                        c[m] += zmuN[z][k0+m] - fmaxf(sj + s2bL[k0+m], 0.f);
                    }
                }
            }
            pa += c.x*W[(k0+0)*E+e] + c.y*W[(k0+1)*E+e]
                + c.z*W[(k0+2)*E+e] + c.w*W[(k0+3)*E+e];
        }
        sQB[q][e] = pa;
        s2bP_r = s2b_r;
        if (nz > 0 && q == 0)
            for (int z = 0; z < nz; ++z) zmuP[z][e] = zmuN[z][e];
        __syncthreads();                                   // B2

        if (it < 3) {
            float s = t2b[e];
            #pragma unroll
            for (int qq = 0; qq < 8; ++qq) s += sQB[qq][e];
            s2b_r = s;          // identical FP order in every thread
        }
    }

    // ===== tail: publish s2b, gsum, zero-row mu4 =====
    if (q == 0) {
        s2b3g[b*E + e] = s2b_r;
        float g = t6b[e];
        #pragma unroll
        for (int qq = 0; qq < 8; ++qq) g += sQB[qq][e];
        float v = fmaxf(g, 0.f) * t5w[e];
        #pragma unroll
        for (int off = 32; off; off >>= 1) v += __shfl_down(v, off, 64);
        if ((t & 63) == 0) sg2[t >> 6] = v;
        for (int z = 0; z < nz; ++z)
            zmu4g[bb + (size_t)zlist[z]*E + e] = zmuP[z][e];
    }
    if (q == 1 && nzs > ZCAP) {
        for (int j = 0; j < NN; ++j) {
            if (zcnt[b*NN + j] > 0 && zmap[j] < 0) {
                float sj = s13g[bb + (size_t)j*E + e];
                zmu4g[bb + (size_t)j*E + e] = fmaxf(sj + s2b_r, 0.f);
            }
        }
    }
    __syncthreads();
    if (t == 0) gsumG[b] = sg2[0] + sg2[1];
}

__global__ __launch_bounds__(1024) void k_p3(
    const float* __restrict__ t5w, const float* __restrict__ t5b,
    const float* __restrict__ t7w, const float* __restrict__ t7b,
    const float* __restrict__ s13g, const int* __restrict__ zcnt,
    const float* __restrict__ s2b3g, const float* __restrict__ gsumG,
    const float* __restrict__ zmu4g,
    float* __restrict__ out)
{
    const int blk = blockIdx.x;
    const int b   = blk >> 4;
    const int bt  = blk & 15;
    const int j0  = bt * 16;
    const int r0  = b*NN + j0;
    const int t   = threadIdx.x;
    const int e   = t & 127;
    const int q   = t >> 7;                // 0..7
    const int w   = t >> 6;                // wave 0..15
    const int l   = t & 63;

    __shared__ __align__(16) float mul[16][E];    // mu4 [row][k]
    __shared__ float sredO[16];

    {   // mu4 rows 2q,2q+1: thread (e,q)
        float s2e = s2b3g[b*E + e];
        #pragma unroll
        for (int rr = 0; rr < 2; ++rr) {
            int row = 2*q + rr;
            float v;
            if (zcnt[r0 + row] > 0)
                v = zmu4g[(size_t)(r0+row)*E + e];
            else
                v = fmaxf(s13g[(size_t)(r0+row)*E + e] + s2e, 0.f);
            mul[row][e] = v;
        }
    }
    __syncthreads();
    if (w < 8) {
        // theta7 matvec, col-blocked: wave w -> rows 2w, 2w+1;
        // lane l -> cols l and l+64; then t5 right-half dot + reduce.
        const int ra = 2*w, rb = 2*w + 1;
        float a00=0.f, a01=0.f, a10=0.f, a11=0.f;
        #pragma unroll 2
        for (int k0 = 0; k0 < E; k0 += 4) {
            f4 m0 = *(const f4*)&mul[ra][k0];
            f4 m1 = *(const f4*)&mul[rb][k0];
            #pragma unroll
            for (int m = 0; m < 4; ++m) {
                float w7A = t7w[(k0+m)*E + l];
                float w7B = t7w[(k0+m)*E + l + 64];
                a00 += m0[m]*w7A;
                a01 += m0[m]*w7B;
                a10 += m1[m]*w7A;
                a11 += m1[m]*w7B;
            }
        }
        float b7A = t7b[l],     b7B = t7b[l+64];
        float w5A = t5w[E+l],   w5B = t5w[E+l+64];
        float v0 = fmaxf(a00 + b7A, 0.f)*w5A + fmaxf(a01 + b7B, 0.f)*w5B;
        float v1 = fmaxf(a10 + b7A, 0.f)*w5A + fmaxf(a11 + b7B, 0.f)*w5B;
        #pragma unroll
        for (int off = 32; off; off >>= 1) {
            v0 += __shfl_down(v0, off, 64);
            v1 += __shfl_down(v1, off, 64);
        }
        if (l == 0) { sredO[ra] = v0; sredO[rb] = v1; }
    }
    __syncthreads();
    if (t < 16)
        out[r0 + t] = sredO[t] + gsumG[b] + t5b[0];
}

extern "C" void kernel_launch(void* const* d_in, const int* in_sizes, int n_in,
                              void* d_out, int out_size, void* d_ws, size_t ws_size,
                              hipStream_t stream) {
    const float* xv  = (const float*)d_in[0];
    const float* Ws  = (const float*)d_in[1];
    const float* t1w = (const float*)d_in[2];  const float* t1b = (const float*)d_in[3];
    const float* t2w = (const float*)d_in[4];  const float* t2b = (const float*)d_in[5];
    const float* t3w = (const float*)d_in[6];  const float* t3b = (const float*)d_in[7];
    const float* t4w = (const float*)d_in[8];  const float* t4b = (const float*)d_in[9];
    const float* t5w = (const float*)d_in[10]; const float* t5b = (const float*)d_in[11];
    const float* t6w = (const float*)d_in[12]; const float* t6b = (const float*)d_in[13];
    const float* t7w = (const float*)d_in[14]; const float* t7b = (const float*)d_in[15];
    const float* lw  = (const float*)d_in[16]; const float* lb  = (const float*)d_in[17];
    float* outp = (float*)d_out;

    float* ws = (float*)d_ws;
    const int RE = NR*E;                    // 524288
    float* s13g  = ws;
    float* zmu4g = ws + RE;
    float* s2b3g = ws + 2*RE;               // BATCH*E
    float* gsumG = s2b3g + BATCH*E;         // BATCH
    int*   zcnt  = (int*)(gsumG + 64);      // NR

    k_p1<<<256, 1024, 0, stream>>>(xv, Ws, t1w, t1b, t3w, t3b, t4w, t4b,
                                   lw, lb, s13g, zcnt);
    k_p2<<<BATCH, 1024, 0, stream>>>(Ws, t2w, t2b, t5w, t6w, t6b,
                                     s13g, zcnt, s2b3g, gsumG, zmu4g);
    k_p3<<<256, 1024, 0, stream>>>(t5w, t5b, t7w, t7b, s13g, zcnt,
                                   s2b3g, gsumG, zmu4g, outp);
}